// Round 1
// baseline (736.272 us; speedup 1.0000x reference)
//
#include <hip/hip_runtime.h>
#include <hip/hip_bf16.h>
#include <math.h>

#define NN 20000          // nodes
#define NE 320000         // edges (without self loops)
#define ET (NE + NN)      // edges + self loops
#define NG 64             // graphs
#define HEADS 4
#define HID 128
#define OUTC (HEADS * HID)   // 512
#define SLOPE 0.2f

__device__ __forceinline__ float lrelu(float v) { return v > 0.f ? v : SLOPE * v; }

// ---------------- CSR build ----------------
__global__ void k_hist(const int* __restrict__ ei, int* __restrict__ deg) {
  int e = blockIdx.x * blockDim.x + threadIdx.x;
  if (e >= ET) return;
  int dst = (e < NE) ? ei[NE + e] : (e - NE);
  atomicAdd(&deg[dst], 1);
}

__global__ void k_scan(const int* __restrict__ deg, int* __restrict__ row_start,
                       int* __restrict__ cursor) {
  __shared__ int sums[1024];
  int tid = threadIdx.x;
  const int PER = (NN + 1023) / 1024;   // 20
  int base = tid * PER;
  int local = 0;
  for (int i = 0; i < PER; ++i) { int idx = base + i; if (idx < NN) local += deg[idx]; }
  sums[tid] = local;
  __syncthreads();
  for (int off = 1; off < 1024; off <<= 1) {
    int v = (tid >= off) ? sums[tid - off] : 0;
    __syncthreads();
    sums[tid] += v;
    __syncthreads();
  }
  int run = sums[tid] - local;  // exclusive prefix
  for (int i = 0; i < PER; ++i) {
    int idx = base + i;
    if (idx < NN) { row_start[idx] = run; cursor[idx] = run; run += deg[idx]; }
  }
  if (tid == 1023) row_start[NN] = sums[1023];
}

__global__ void k_scatter(const int* __restrict__ ei, int* __restrict__ cursor,
                          int* __restrict__ csr_src) {
  int e = blockIdx.x * blockDim.x + threadIdx.x;
  if (e >= ET) return;
  int src, dst;
  if (e < NE) { src = ei[e]; dst = ei[NE + e]; }
  else        { src = e - NE; dst = src; }
  int pos = atomicAdd(&cursor[dst], 1);
  csr_src[pos] = src;
}

// ---------------- dense GEMM h = x @ W,  W is [K, 512] ----------------
template <int K>
__global__ void k_gemm(const float* __restrict__ x, const float* __restrict__ W,
                       float* __restrict__ h) {
  __shared__ float sA[16 * K];
  int tid = threadIdx.x;                  // 256 threads
  int r0 = blockIdx.y * 16;
  int col = blockIdx.x * 256 + tid;       // 512 cols total, gridDim.x = 2
  for (int i = tid; i < 16 * K; i += 256) {
    int r = i / K, k = i % K;
    int row = r0 + r;
    sA[i] = (row < NN) ? x[row * K + k] : 0.f;
  }
  __syncthreads();
  float acc[16];
#pragma unroll
  for (int r = 0; r < 16; ++r) acc[r] = 0.f;
  for (int k = 0; k < K; ++k) {
    float w = W[k * OUTC + col];
#pragma unroll
    for (int r = 0; r < 16; ++r) acc[r] += sA[r * K + k] * w;
  }
#pragma unroll
  for (int r = 0; r < 16; ++r) {
    int row = r0 + r;
    if (row < NN) h[row * OUTC + col] = acc[r];
  }
}

// ---------------- attention logits per node ----------------
__global__ void k_esd(const float* __restrict__ h, const float* __restrict__ as,
                      const float* __restrict__ ad, float* __restrict__ e_src,
                      float* __restrict__ e_dst) {
  int n = blockIdx.x;
  int lane = threadIdx.x;  // 64
  for (int hh = 0; hh < HEADS; ++hh) {
    float ps = 0.f, pd = 0.f;
    for (int c = lane; c < HID; c += 64) {
      float hv = h[n * OUTC + hh * HID + c];
      ps += hv * as[hh * HID + c];
      pd += hv * ad[hh * HID + c];
    }
#pragma unroll
    for (int off = 32; off > 0; off >>= 1) {
      ps += __shfl_down(ps, off);
      pd += __shfl_down(pd, off);
    }
    if (lane == 0) { e_src[n * HEADS + hh] = ps; e_dst[n * HEADS + hh] = pd; }
  }
}

// ---------------- fused edge-softmax + aggregation + head-mean + bias + relu ----------------
__global__ void k_agg(const float* __restrict__ h, const float* __restrict__ es,
                      const float* __restrict__ ed, const int* __restrict__ row_start,
                      const int* __restrict__ csr_src, const float* __restrict__ bias,
                      float* __restrict__ xout) {
  const int CH = 128;  // edge chunk
  __shared__ float s_ed[4], smax[4], ssum[4];
  __shared__ float s_part[16];
  __shared__ int s_srcs[CH];
  __shared__ float s_ex[CH * 4];
  __shared__ float s_out[OUTC];
  int n = blockIdx.x, tid = threadIdx.x;  // 256 threads
  int start = row_start[n];
  int deg = row_start[n + 1] - start;
  if (tid < 4) { s_ed[tid] = ed[n * 4 + tid]; ssum[tid] = 0.f; }
  __syncthreads();
  int hcls = tid & 3;   // head class for edge loops (stride 256 keeps it fixed)
  int wid  = tid >> 6;  // wave id
  // ---- pass 1: per-head max over incoming edges ----
  float lmax = -INFINITY;
  for (int k = tid; k < deg * 4; k += 256) {
    int s = csr_src[start + (k >> 2)];
    lmax = fmaxf(lmax, lrelu(es[s * 4 + hcls] + s_ed[hcls]));
  }
#pragma unroll
  for (int off = 4; off < 64; off <<= 1) lmax = fmaxf(lmax, __shfl_xor(lmax, off));
  if ((tid & 63) < 4) s_part[wid * 4 + hcls] = lmax;
  __syncthreads();
  if (tid < 4)
    smax[tid] = fmaxf(fmaxf(s_part[tid], s_part[4 + tid]),
                      fmaxf(s_part[8 + tid], s_part[12 + tid]));
  __syncthreads();
  // ---- chunked pass 2: exp + denom, then weighted gather ----
  int ohead = tid >> 6;          // this thread's output head (channels 2t, 2t+1)
  float acc0 = 0.f, acc1 = 0.f;
  for (int cb = 0; cb < deg; cb += CH) {
    int m = min(CH, deg - cb);
    float lsum = 0.f;
    for (int k = tid; k < m * 4; k += 256) {
      int pos = start + cb + (k >> 2);
      int s = csr_src[pos];
      float v = lrelu(es[s * 4 + hcls] + s_ed[hcls]);
      float ex = __expf(v - smax[hcls]);
      s_ex[k] = ex;
      lsum += ex;
      if (hcls == 0) s_srcs[k >> 2] = s;
    }
#pragma unroll
    for (int off = 4; off < 64; off <<= 1) lsum += __shfl_xor(lsum, off);
    if ((tid & 63) < 4) s_part[wid * 4 + hcls] = lsum;
    __syncthreads();
    if (tid < 4) ssum[tid] += s_part[tid] + s_part[4 + tid] + s_part[8 + tid] + s_part[12 + tid];
    for (int j = 0; j < m; ++j) {
      int s = s_srcs[j];
      const float2 hv = *reinterpret_cast<const float2*>(&h[s * OUTC + tid * 2]);
      float a = s_ex[j * 4 + ohead];
      acc0 += a * hv.x;
      acc1 += a * hv.y;
    }
    __syncthreads();
  }
  float inv = 1.f / ssum[ohead];
  s_out[tid * 2]     = acc0 * inv;
  s_out[tid * 2 + 1] = acc1 * inv;
  __syncthreads();
  if (tid < HID) {
    float v = (s_out[tid] + s_out[HID + tid] + s_out[2 * HID + tid] + s_out[3 * HID + tid]) * 0.25f
              + bias[tid];
    xout[n * HID + tid] = v > 0.f ? v : 0.f;
  }
}

// ---------------- global mean pool + MLP head ----------------
__global__ void k_pool_mlp(const float* __restrict__ x, const int* __restrict__ batch,
                           const float* __restrict__ bst, const float* __restrict__ M1,
                           const float* __restrict__ mb1, const float* __restrict__ M2,
                           const float* __restrict__ mb2, const float* __restrict__ M3,
                           const float* __restrict__ mb3, float* __restrict__ out) {
  int g = blockIdx.x, tid = threadIdx.x;  // 128 threads
  // lower_bound(g), lower_bound(g+1) in sorted batch
  int lo = 0, hi = NN;
  while (lo < hi) { int mid = (lo + hi) >> 1; if (batch[mid] < g) lo = mid + 1; else hi = mid; }
  int s = lo;
  lo = s; hi = NN;
  while (lo < hi) { int mid = (lo + hi) >> 1; if (batch[mid] < g + 1) lo = mid + 1; else hi = mid; }
  int e = lo;
  float acc = 0.f;
  for (int node = s; node < e; ++node) acc += x[node * HID + tid];
  float cnt = (float)(e - s);
  float pooled = acc / fmaxf(cnt, 1.f);
  __shared__ float z[HID + 1];
  __shared__ float z1[HID];
  __shared__ float z2[64];
  z[tid] = pooled;
  if (tid == 0) z[HID] = log1pf(bst[g]);
  __syncthreads();
  float a1 = mb1[tid];
  for (int k = 0; k < HID + 1; ++k) a1 += z[k] * M1[k * HID + tid];
  z1[tid] = a1 > 0.f ? a1 : 0.f;
  __syncthreads();
  if (tid < 64) {
    float a2 = mb2[tid];
    for (int k = 0; k < HID; ++k) a2 += z1[k] * M2[k * 64 + tid];
    z2[tid] = a2 > 0.f ? a2 : 0.f;
  }
  __syncthreads();
  if (tid < 2) {
    float a3 = mb3[tid];
    for (int k = 0; k < 64; ++k) a3 += z2[k] * M3[k * 2 + tid];
    out[g * 2 + tid] = a3;
  }
}

extern "C" void kernel_launch(void* const* d_in, const int* in_sizes, int n_in,
                              void* d_out, int out_size, void* d_ws, size_t ws_size,
                              hipStream_t stream) {
  const float* x   = (const float*)d_in[0];
  const int*   ei  = (const int*)d_in[1];
  const int*   bat = (const int*)d_in[2];
  const float* bst = (const float*)d_in[3];
  const float* W1 = (const float*)d_in[4];
  const float* as1 = (const float*)d_in[5];
  const float* ad1 = (const float*)d_in[6];
  const float* b1 = (const float*)d_in[7];
  const float* W2 = (const float*)d_in[8];
  const float* as2 = (const float*)d_in[9];
  const float* ad2 = (const float*)d_in[10];
  const float* b2 = (const float*)d_in[11];
  const float* W3 = (const float*)d_in[12];
  const float* as3 = (const float*)d_in[13];
  const float* ad3 = (const float*)d_in[14];
  const float* b3 = (const float*)d_in[15];
  const float* M1 = (const float*)d_in[16];
  const float* mb1 = (const float*)d_in[17];
  const float* M2 = (const float*)d_in[18];
  const float* mb2 = (const float*)d_in[19];
  const float* M3 = (const float*)d_in[20];
  const float* mb3 = (const float*)d_in[21];
  float* out = (float*)d_out;

  char* ws = (char*)d_ws;
  auto alloc = [&](size_t bytes) -> void* {
    void* p = (void*)ws;
    ws += (bytes + 255) & ~(size_t)255;
    return p;
  };
  float* h_buf    = (float*)alloc((size_t)NN * OUTC * 4);
  float* x_buf    = (float*)alloc((size_t)NN * HID * 4);
  float* e_src    = (float*)alloc((size_t)NN * 4 * 4);
  float* e_dst    = (float*)alloc((size_t)NN * 4 * 4);
  int*   deg      = (int*)alloc((size_t)NN * 4);
  int*   rowst    = (int*)alloc((size_t)(NN + 1) * 4);
  int*   cursor   = (int*)alloc((size_t)NN * 4);
  int*   csr      = (int*)alloc((size_t)ET * 4);

  // CSR by destination (depends only on edge_index; rebuilt deterministically each call)
  hipMemsetAsync(deg, 0, (size_t)NN * 4, stream);
  k_hist<<<(ET + 255) / 256, 256, 0, stream>>>(ei, deg);
  k_scan<<<1, 1024, 0, stream>>>(deg, rowst, cursor);
  k_scatter<<<(ET + 255) / 256, 256, 0, stream>>>(ei, cursor, csr);

  // layer 1
  k_gemm<12><<<dim3(2, (NN + 15) / 16), 256, 0, stream>>>(x, W1, h_buf);
  k_esd<<<NN, 64, 0, stream>>>(h_buf, as1, ad1, e_src, e_dst);
  k_agg<<<NN, 256, 0, stream>>>(h_buf, e_src, e_dst, rowst, csr, b1, x_buf);
  // layer 2
  k_gemm<128><<<dim3(2, (NN + 15) / 16), 256, 0, stream>>>(x_buf, W2, h_buf);
  k_esd<<<NN, 64, 0, stream>>>(h_buf, as2, ad2, e_src, e_dst);
  k_agg<<<NN, 256, 0, stream>>>(h_buf, e_src, e_dst, rowst, csr, b2, x_buf);
  // layer 3
  k_gemm<128><<<dim3(2, (NN + 15) / 16), 256, 0, stream>>>(x_buf, W3, h_buf);
  k_esd<<<NN, 64, 0, stream>>>(h_buf, as3, ad3, e_src, e_dst);
  k_agg<<<NN, 256, 0, stream>>>(h_buf, e_src, e_dst, rowst, csr, b3, x_buf);
  // pool + MLP
  k_pool_mlp<<<NG, 128, 0, stream>>>(x_buf, bat, bst, M1, mb1, M2, mb2, M3, mb3, out);
}

// Round 2
// 586.722 us; speedup vs baseline: 1.2549x; 1.2549x over previous
//
#include <hip/hip_runtime.h>
#include <hip/hip_bf16.h>
#include <math.h>

#define NN 20000          // nodes
#define NE 320000         // edges (without self loops)
#define ET (NE + NN)      // edges + self loops
#define NG 64             // graphs
#define HEADS 4
#define HID 128
#define OUTC (HEADS * HID)   // 512
#define SLOPE 0.2f

__device__ __forceinline__ float lrelu(float v) { return v > 0.f ? v : SLOPE * v; }

// ---------------- CSR build ----------------
__global__ void k_hist(const int* __restrict__ ei, int* __restrict__ deg) {
  int e = blockIdx.x * blockDim.x + threadIdx.x;
  if (e >= ET) return;
  int dst = (e < NE) ? ei[NE + e] : (e - NE);
  atomicAdd(&deg[dst], 1);
}

__global__ void k_scan(const int* __restrict__ deg, int* __restrict__ row_start,
                       int* __restrict__ cursor) {
  __shared__ int sums[1024];
  int tid = threadIdx.x;
  const int PER = (NN + 1023) / 1024;   // 20
  int base = tid * PER;
  int local = 0;
  for (int i = 0; i < PER; ++i) { int idx = base + i; if (idx < NN) local += deg[idx]; }
  sums[tid] = local;
  __syncthreads();
  for (int off = 1; off < 1024; off <<= 1) {
    int v = (tid >= off) ? sums[tid - off] : 0;
    __syncthreads();
    sums[tid] += v;
    __syncthreads();
  }
  int run = sums[tid] - local;  // exclusive prefix
  for (int i = 0; i < PER; ++i) {
    int idx = base + i;
    if (idx < NN) { row_start[idx] = run; cursor[idx] = run; run += deg[idx]; }
  }
  if (tid == 1023) row_start[NN] = sums[1023];
}

__global__ void k_scatter(const int* __restrict__ ei, int* __restrict__ cursor,
                          int* __restrict__ csr_src) {
  int e = blockIdx.x * blockDim.x + threadIdx.x;
  if (e >= ET) return;
  int src, dst;
  if (e < NE) { src = ei[e]; dst = ei[NE + e]; }
  else        { src = e - NE; dst = src; }
  int pos = atomicAdd(&cursor[dst], 1);
  csr_src[pos] = src;
}

// ---------------- tiled GEMM: h = x @ W,  x [NN,K], W [K,512] ----------------
// 64x64 tile, 256 threads, 4x4 register blocking, A transposed in LDS.
template <int K, int BK>
__global__ void k_gemm_t(const float* __restrict__ x, const float* __restrict__ W,
                         float* __restrict__ h) {
  const int BM = 64, BN = 64;
  __shared__ float sAT[BK][BM + 4];
  __shared__ float sB[BK][BN];
  int tid = threadIdx.x;
  int r0 = blockIdx.y * BM;
  int cb = blockIdx.x * BN;
  int tx = tid & 15, ty = tid >> 4;
  int m0 = ty * 4, n0 = tx * 4;
  float acc[4][4] = {};
  for (int k0 = 0; k0 < K; k0 += BK) {
    // stage A (transposed)
    const int AF4 = BM * BK / 4;
    for (int idx = tid; idx < AF4; idx += 256) {
      int r = idx / (BK / 4);
      int kq = idx % (BK / 4);
      int row = r0 + r;
      float4 v = make_float4(0.f, 0.f, 0.f, 0.f);
      if (row < NN) v = *reinterpret_cast<const float4*>(&x[(size_t)row * K + k0 + kq * 4]);
      sAT[kq * 4 + 0][r] = v.x;
      sAT[kq * 4 + 1][r] = v.y;
      sAT[kq * 4 + 2][r] = v.z;
      sAT[kq * 4 + 3][r] = v.w;
    }
    // stage B
    const int BF4 = BK * BN / 4;
    for (int idx = tid; idx < BF4; idx += 256) {
      int k = idx / 16, nq = idx & 15;
      float4 v = *reinterpret_cast<const float4*>(&W[(size_t)(k0 + k) * OUTC + cb + nq * 4]);
      *reinterpret_cast<float4*>(&sB[k][nq * 4]) = v;
    }
    __syncthreads();
#pragma unroll 4
    for (int kk = 0; kk < BK; ++kk) {
      float4 a = *reinterpret_cast<const float4*>(&sAT[kk][m0]);
      float4 b = *reinterpret_cast<const float4*>(&sB[kk][n0]);
      acc[0][0] += a.x * b.x; acc[0][1] += a.x * b.y; acc[0][2] += a.x * b.z; acc[0][3] += a.x * b.w;
      acc[1][0] += a.y * b.x; acc[1][1] += a.y * b.y; acc[1][2] += a.y * b.z; acc[1][3] += a.y * b.w;
      acc[2][0] += a.z * b.x; acc[2][1] += a.z * b.y; acc[2][2] += a.z * b.z; acc[2][3] += a.z * b.w;
      acc[3][0] += a.w * b.x; acc[3][1] += a.w * b.y; acc[3][2] += a.w * b.z; acc[3][3] += a.w * b.w;
    }
    __syncthreads();
  }
#pragma unroll
  for (int i = 0; i < 4; ++i) {
    int row = r0 + m0 + i;
    if (row < NN) {
      float4 v = make_float4(acc[i][0], acc[i][1], acc[i][2], acc[i][3]);
      *reinterpret_cast<float4*>(&h[(size_t)row * OUTC + cb + n0]) = v;
    }
  }
}

// ---------------- attention logits per node (float4, 128 thr/node) ----------------
__global__ void k_esd(const float* __restrict__ h, const float* __restrict__ as,
                      const float* __restrict__ ad, float* __restrict__ e_src,
                      float* __restrict__ e_dst) {
  int n = blockIdx.x;
  int tid = threadIdx.x;       // 128
  int head = tid >> 5, q = tid & 31;
  float4 hv = *reinterpret_cast<const float4*>(&h[(size_t)n * OUTC + head * HID + q * 4]);
  float4 av = *reinterpret_cast<const float4*>(&as[head * HID + q * 4]);
  float4 dv = *reinterpret_cast<const float4*>(&ad[head * HID + q * 4]);
  float ps = hv.x * av.x + hv.y * av.y + hv.z * av.z + hv.w * av.w;
  float pd = hv.x * dv.x + hv.y * dv.y + hv.z * dv.z + hv.w * dv.w;
#pragma unroll
  for (int off = 1; off < 32; off <<= 1) {
    ps += __shfl_xor(ps, off);
    pd += __shfl_xor(pd, off);
  }
  if (q == 0) { e_src[n * HEADS + head] = ps; e_dst[n * HEADS + head] = pd; }
}

// ---------------- fused edge-softmax + aggregation + head-mean + bias + relu ----------------
__global__ void k_agg(const float* __restrict__ h, const float* __restrict__ es,
                      const float* __restrict__ ed, const int* __restrict__ row_start,
                      const int* __restrict__ csr_src, const float* __restrict__ bias,
                      float* __restrict__ xout) {
  const int CH = 128;  // edge chunk
  __shared__ float s_ed[4], smax[4], ssum[4];
  __shared__ float s_part[16];
  __shared__ int s_srcs[CH];
  __shared__ float s_ex[CH * 4];
  __shared__ float s_out[2][OUTC];
  int n = blockIdx.x, tid = threadIdx.x;  // 256 threads
  int start = row_start[n];
  int deg = row_start[n + 1] - start;
  if (tid < 4) { s_ed[tid] = ed[n * 4 + tid]; ssum[tid] = 0.f; }
  __syncthreads();
  int hcls = tid & 3;   // head class for edge-logit loops (stride 256 keeps it fixed)
  int wid  = tid >> 6;  // wave id
  // ---- pass 1: per-head max over incoming edges ----
  float lmax = -INFINITY;
  for (int k = tid; k < deg * 4; k += 256) {
    int s = csr_src[start + (k >> 2)];
    lmax = fmaxf(lmax, lrelu(es[s * 4 + hcls] + s_ed[hcls]));
  }
#pragma unroll
  for (int off = 4; off < 64; off <<= 1) lmax = fmaxf(lmax, __shfl_xor(lmax, off));
  if ((tid & 63) < 4) s_part[wid * 4 + hcls] = lmax;
  __syncthreads();
  if (tid < 4)
    smax[tid] = fmaxf(fmaxf(s_part[tid], s_part[4 + tid]),
                      fmaxf(s_part[8 + tid], s_part[12 + tid]));
  __syncthreads();
  // ---- chunked pass 2: exp + denom, then weighted float4 gather (2 edges/iter) ----
  int cq = tid & 127;        // channel quad 0..127 (channels cq*4 .. cq*4+3)
  int par = tid >> 7;        // edge parity handled by this thread
  int c0 = cq * 4;
  int head = cq >> 5;        // which head these channels belong to
  float a0 = 0.f, a1 = 0.f, a2 = 0.f, a3 = 0.f;
  for (int cb = 0; cb < deg; cb += CH) {
    int m = min(CH, deg - cb);
    float lsum = 0.f;
    for (int k = tid; k < m * 4; k += 256) {
      int pos = start + cb + (k >> 2);
      int s = csr_src[pos];
      float v = lrelu(es[s * 4 + hcls] + s_ed[hcls]);
      float ex = __expf(v - smax[hcls]);
      s_ex[k] = ex;
      lsum += ex;
      if (hcls == 0) s_srcs[k >> 2] = s;
    }
#pragma unroll
    for (int off = 4; off < 64; off <<= 1) lsum += __shfl_xor(lsum, off);
    if ((tid & 63) < 4) s_part[wid * 4 + hcls] = lsum;
    __syncthreads();
    if (tid < 4) ssum[tid] += s_part[tid] + s_part[4 + tid] + s_part[8 + tid] + s_part[12 + tid];
    for (int jj = 0; jj < m; jj += 2) {
      int j = jj + par;
      if (j < m) {
        int s = s_srcs[j];
        const float4 hv = *reinterpret_cast<const float4*>(&h[(size_t)s * OUTC + c0]);
        float a = s_ex[j * 4 + head];
        a0 += a * hv.x; a1 += a * hv.y; a2 += a * hv.z; a3 += a * hv.w;
      }
    }
    __syncthreads();
  }
  float inv = 1.f / ssum[head];
  s_out[par][c0 + 0] = a0 * inv;
  s_out[par][c0 + 1] = a1 * inv;
  s_out[par][c0 + 2] = a2 * inv;
  s_out[par][c0 + 3] = a3 * inv;
  __syncthreads();
  if (tid < HID) {
    float v = s_out[0][tid] + s_out[1][tid]
            + s_out[0][HID + tid] + s_out[1][HID + tid]
            + s_out[0][2 * HID + tid] + s_out[1][2 * HID + tid]
            + s_out[0][3 * HID + tid] + s_out[1][3 * HID + tid];
    v = v * 0.25f + bias[tid];
    xout[(size_t)n * HID + tid] = v > 0.f ? v : 0.f;
  }
}

// ---------------- global mean pool + MLP head ----------------
__global__ void k_pool_mlp(const float* __restrict__ x, const int* __restrict__ batch,
                           const float* __restrict__ bst, const float* __restrict__ M1,
                           const float* __restrict__ mb1, const float* __restrict__ M2,
                           const float* __restrict__ mb2, const float* __restrict__ M3,
                           const float* __restrict__ mb3, float* __restrict__ out) {
  int g = blockIdx.x, tid = threadIdx.x;  // 128 threads
  int lo = 0, hi = NN;
  while (lo < hi) { int mid = (lo + hi) >> 1; if (batch[mid] < g) lo = mid + 1; else hi = mid; }
  int s = lo;
  lo = s; hi = NN;
  while (lo < hi) { int mid = (lo + hi) >> 1; if (batch[mid] < g + 1) lo = mid + 1; else hi = mid; }
  int e = lo;
  float acc = 0.f;
  for (int node = s; node < e; ++node) acc += x[(size_t)node * HID + tid];
  float cnt = (float)(e - s);
  float pooled = acc / fmaxf(cnt, 1.f);
  __shared__ float z[HID + 1];
  __shared__ float z1[HID];
  __shared__ float z2[64];
  z[tid] = pooled;
  if (tid == 0) z[HID] = log1pf(bst[g]);
  __syncthreads();
  float a1 = mb1[tid];
  for (int k = 0; k < HID + 1; ++k) a1 += z[k] * M1[k * HID + tid];
  z1[tid] = a1 > 0.f ? a1 : 0.f;
  __syncthreads();
  if (tid < 64) {
    float a2 = mb2[tid];
    for (int k = 0; k < HID; ++k) a2 += z1[k] * M2[k * 64 + tid];
    z2[tid] = a2 > 0.f ? a2 : 0.f;
  }
  __syncthreads();
  if (tid < 2) {
    float a3 = mb3[tid];
    for (int k = 0; k < 64; ++k) a3 += z2[k] * M3[k * 2 + tid];
    out[g * 2 + tid] = a3;
  }
}

extern "C" void kernel_launch(void* const* d_in, const int* in_sizes, int n_in,
                              void* d_out, int out_size, void* d_ws, size_t ws_size,
                              hipStream_t stream) {
  const float* x   = (const float*)d_in[0];
  const int*   ei  = (const int*)d_in[1];
  const int*   bat = (const int*)d_in[2];
  const float* bst = (const float*)d_in[3];
  const float* W1 = (const float*)d_in[4];
  const float* as1 = (const float*)d_in[5];
  const float* ad1 = (const float*)d_in[6];
  const float* b1 = (const float*)d_in[7];
  const float* W2 = (const float*)d_in[8];
  const float* as2 = (const float*)d_in[9];
  const float* ad2 = (const float*)d_in[10];
  const float* b2 = (const float*)d_in[11];
  const float* W3 = (const float*)d_in[12];
  const float* as3 = (const float*)d_in[13];
  const float* ad3 = (const float*)d_in[14];
  const float* b3 = (const float*)d_in[15];
  const float* M1 = (const float*)d_in[16];
  const float* mb1 = (const float*)d_in[17];
  const float* M2 = (const float*)d_in[18];
  const float* mb2 = (const float*)d_in[19];
  const float* M3 = (const float*)d_in[20];
  const float* mb3 = (const float*)d_in[21];
  float* out = (float*)d_out;

  char* ws = (char*)d_ws;
  auto alloc = [&](size_t bytes) -> void* {
    void* p = (void*)ws;
    ws += (bytes + 255) & ~(size_t)255;
    return p;
  };
  float* h_buf  = (float*)alloc((size_t)NN * OUTC * 4);
  float* x_buf  = (float*)alloc((size_t)NN * HID * 4);
  float* e_src  = (float*)alloc((size_t)NN * 4 * 4);
  float* e_dst  = (float*)alloc((size_t)NN * 4 * 4);
  int*   deg    = (int*)alloc((size_t)NN * 4);
  int*   rowst  = (int*)alloc((size_t)(NN + 1) * 4);
  int*   cursor = (int*)alloc((size_t)NN * 4);
  int*   csr    = (int*)alloc((size_t)ET * 4);

  // CSR by destination
  hipMemsetAsync(deg, 0, (size_t)NN * 4, stream);
  k_hist<<<(ET + 255) / 256, 256, 0, stream>>>(ei, deg);
  k_scan<<<1, 1024, 0, stream>>>(deg, rowst, cursor);
  k_scatter<<<(ET + 255) / 256, 256, 0, stream>>>(ei, cursor, csr);

  dim3 ggrid(OUTC / 64, (NN + 63) / 64);
  // layer 1
  k_gemm_t<12, 12><<<ggrid, 256, 0, stream>>>(x, W1, h_buf);
  k_esd<<<NN, 128, 0, stream>>>(h_buf, as1, ad1, e_src, e_dst);
  k_agg<<<NN, 256, 0, stream>>>(h_buf, e_src, e_dst, rowst, csr, b1, x_buf);
  // layer 2
  k_gemm_t<128, 64><<<ggrid, 256, 0, stream>>>(x_buf, W2, h_buf);
  k_esd<<<NN, 128, 0, stream>>>(h_buf, as2, ad2, e_src, e_dst);
  k_agg<<<NN, 256, 0, stream>>>(h_buf, e_src, e_dst, rowst, csr, b2, x_buf);
  // layer 3
  k_gemm_t<128, 64><<<ggrid, 256, 0, stream>>>(x_buf, W3, h_buf);
  k_esd<<<NN, 128, 0, stream>>>(h_buf, as3, ad3, e_src, e_dst);
  k_agg<<<NN, 256, 0, stream>>>(h_buf, e_src, e_dst, rowst, csr, b3, x_buf);
  // pool + MLP
  k_pool_mlp<<<NG, 128, 0, stream>>>(x_buf, bat, bst, M1, mb1, M2, mb2, M3, mb3, out);
}

// Round 3
// 528.802 us; speedup vs baseline: 1.3923x; 1.1095x over previous
//
#include <hip/hip_runtime.h>
#include <hip/hip_bf16.h>
#include <math.h>

#define NN 20000          // nodes
#define NE 320000         // edges (without self loops)
#define ET (NE + NN)      // edges + self loops
#define NG 64             // graphs
#define HEADS 4
#define HID 128
#define OUTC (HEADS * HID)   // 512
#define SLOPE 0.2f
#define NINF (-1e30f)

__device__ __forceinline__ float lrelu(float v) { return v > 0.f ? v : SLOPE * v; }

// ---------------- CSR build ----------------
__global__ void k_hist(const int* __restrict__ ei, int* __restrict__ deg) {
  int e = blockIdx.x * blockDim.x + threadIdx.x;
  if (e >= ET) return;
  int dst = (e < NE) ? ei[NE + e] : (e - NE);
  atomicAdd(&deg[dst], 1);
}

__global__ void k_scan(const int* __restrict__ deg, int* __restrict__ row_start,
                       int* __restrict__ cursor) {
  __shared__ int sums[1024];
  int tid = threadIdx.x;
  const int PER = (NN + 1023) / 1024;   // 20
  int base = tid * PER;
  int local = 0;
  for (int i = 0; i < PER; ++i) { int idx = base + i; if (idx < NN) local += deg[idx]; }
  sums[tid] = local;
  __syncthreads();
  for (int off = 1; off < 1024; off <<= 1) {
    int v = (tid >= off) ? sums[tid - off] : 0;
    __syncthreads();
    sums[tid] += v;
    __syncthreads();
  }
  int run = sums[tid] - local;  // exclusive prefix
  for (int i = 0; i < PER; ++i) {
    int idx = base + i;
    if (idx < NN) { row_start[idx] = run; cursor[idx] = run; run += deg[idx]; }
  }
  if (tid == 1023) row_start[NN] = sums[1023];
}

__global__ void k_scatter(const int* __restrict__ ei, int* __restrict__ cursor,
                          int* __restrict__ csr_src) {
  int e = blockIdx.x * blockDim.x + threadIdx.x;
  if (e >= ET) return;
  int src, dst;
  if (e < NE) { src = ei[e]; dst = ei[NE + e]; }
  else        { src = e - NE; dst = src; }
  int pos = atomicAdd(&cursor[dst], 1);
  csr_src[pos] = src;
}

// ---------------- tiled GEMM: h = x @ W,  x [NN,K], W [K,512] ----------------
template <int K, int BK>
__global__ void k_gemm_t(const float* __restrict__ x, const float* __restrict__ W,
                         float* __restrict__ h) {
  const int BM = 64, BN = 64;
  __shared__ float sAT[BK][BM + 4];
  __shared__ float sB[BK][BN];
  int tid = threadIdx.x;
  int r0 = blockIdx.y * BM;
  int cb = blockIdx.x * BN;
  int tx = tid & 15, ty = tid >> 4;
  int m0 = ty * 4, n0 = tx * 4;
  float acc[4][4] = {};
  for (int k0 = 0; k0 < K; k0 += BK) {
    const int AF4 = BM * BK / 4;
    for (int idx = tid; idx < AF4; idx += 256) {
      int r = idx / (BK / 4);
      int kq = idx % (BK / 4);
      int row = r0 + r;
      float4 v = make_float4(0.f, 0.f, 0.f, 0.f);
      if (row < NN) v = *reinterpret_cast<const float4*>(&x[(size_t)row * K + k0 + kq * 4]);
      sAT[kq * 4 + 0][r] = v.x;
      sAT[kq * 4 + 1][r] = v.y;
      sAT[kq * 4 + 2][r] = v.z;
      sAT[kq * 4 + 3][r] = v.w;
    }
    const int BF4 = BK * BN / 4;
    for (int idx = tid; idx < BF4; idx += 256) {
      int k = idx / 16, nq = idx & 15;
      float4 v = *reinterpret_cast<const float4*>(&W[(size_t)(k0 + k) * OUTC + cb + nq * 4]);
      *reinterpret_cast<float4*>(&sB[k][nq * 4]) = v;
    }
    __syncthreads();
#pragma unroll 4
    for (int kk = 0; kk < BK; ++kk) {
      float4 a = *reinterpret_cast<const float4*>(&sAT[kk][m0]);
      float4 b = *reinterpret_cast<const float4*>(&sB[kk][n0]);
      acc[0][0] += a.x * b.x; acc[0][1] += a.x * b.y; acc[0][2] += a.x * b.z; acc[0][3] += a.x * b.w;
      acc[1][0] += a.y * b.x; acc[1][1] += a.y * b.y; acc[1][2] += a.y * b.z; acc[1][3] += a.y * b.w;
      acc[2][0] += a.z * b.x; acc[2][1] += a.z * b.y; acc[2][2] += a.z * b.z; acc[2][3] += a.z * b.w;
      acc[3][0] += a.w * b.x; acc[3][1] += a.w * b.y; acc[3][2] += a.w * b.z; acc[3][3] += a.w * b.w;
    }
    __syncthreads();
  }
#pragma unroll
  for (int i = 0; i < 4; ++i) {
    int row = r0 + m0 + i;
    if (row < NN) {
      float4 v = make_float4(acc[i][0], acc[i][1], acc[i][2], acc[i][3]);
      *reinterpret_cast<float4*>(&h[(size_t)row * OUTC + cb + n0]) = v;
    }
  }
}

// ---------------- attention logits per node (float4, 128 thr/node) ----------------
__global__ void k_esd(const float* __restrict__ h, const float* __restrict__ as,
                      const float* __restrict__ ad, float* __restrict__ e_src,
                      float* __restrict__ e_dst) {
  int n = blockIdx.x;
  int tid = threadIdx.x;       // 128
  int head = tid >> 5, q = tid & 31;
  float4 hv = *reinterpret_cast<const float4*>(&h[(size_t)n * OUTC + head * HID + q * 4]);
  float4 av = *reinterpret_cast<const float4*>(&as[head * HID + q * 4]);
  float4 dv = *reinterpret_cast<const float4*>(&ad[head * HID + q * 4]);
  float ps = hv.x * av.x + hv.y * av.y + hv.z * av.z + hv.w * av.w;
  float pd = hv.x * dv.x + hv.y * dv.y + hv.z * dv.z + hv.w * dv.w;
#pragma unroll
  for (int off = 1; off < 32; off <<= 1) {
    ps += __shfl_xor(ps, off);
    pd += __shfl_xor(pd, off);
  }
  if (q == 0) { e_src[n * HEADS + head] = ps; e_dst[n * HEADS + head] = pd; }
}

// ---------------- fused edge-softmax + aggregation: ONE WAVE PER NODE ----------------
// 4 independent waves per block (no barriers, no LDS). Lane owns 8 channels.
// Online softmax over edge chunks of 64 (one edge per lane).
__global__ void __launch_bounds__(256) k_agg(
    const float* __restrict__ h, const float* __restrict__ es,
    const float* __restrict__ ed, const int* __restrict__ row_start,
    const int* __restrict__ csr_src, const float* __restrict__ bias,
    float* __restrict__ xout) {
  int wid = threadIdx.x >> 6;
  int lane = threadIdx.x & 63;
  int n = blockIdx.x * 4 + wid;
  if (n >= NN) return;                      // wave-uniform exit; no barriers anywhere
  int start = row_start[n];
  int deg = row_start[n + 1] - start;
  float4 edv = *reinterpret_cast<const float4*>(&ed[(size_t)n * 4]);
  int head = lane >> 4;                     // channels c0..c0+7 all in this head
  int c0 = lane * 8;
  float4 accA = make_float4(0.f, 0.f, 0.f, 0.f);
  float4 accB = make_float4(0.f, 0.f, 0.f, 0.f);
  float m0 = NINF, m1 = NINF, m2 = NINF, m3 = NINF;
  float d0 = 0.f, d1 = 0.f, d2 = 0.f, d3 = 0.f;

  for (int cb = 0; cb < deg; cb += 64) {
    int m = min(64, deg - cb);
    int s = 0;
    float l0 = NINF, l1 = NINF, l2 = NINF, l3 = NINF;
    if (lane < m) {
      s = csr_src[start + cb + lane];
      float4 e4 = *reinterpret_cast<const float4*>(&es[(size_t)s * 4]);
      l0 = lrelu(e4.x + edv.x);
      l1 = lrelu(e4.y + edv.y);
      l2 = lrelu(e4.z + edv.z);
      l3 = lrelu(e4.w + edv.w);
    }
    // chunk max across 64 lanes
    float c0m = l0, c1m = l1, c2m = l2, c3m = l3;
#pragma unroll
    for (int off = 1; off < 64; off <<= 1) {
      c0m = fmaxf(c0m, __shfl_xor(c0m, off));
      c1m = fmaxf(c1m, __shfl_xor(c1m, off));
      c2m = fmaxf(c2m, __shfl_xor(c2m, off));
      c3m = fmaxf(c3m, __shfl_xor(c3m, off));
    }
    float nm0 = fmaxf(m0, c0m), nm1 = fmaxf(m1, c1m);
    float nm2 = fmaxf(m2, c2m), nm3 = fmaxf(m3, c3m);
    float sc0 = __expf(m0 - nm0), sc1 = __expf(m1 - nm1);
    float sc2 = __expf(m2 - nm2), sc3 = __expf(m3 - nm3);
    float ex0 = 0.f, ex1 = 0.f, ex2 = 0.f, ex3 = 0.f;
    if (lane < m) {
      ex0 = __expf(l0 - nm0);
      ex1 = __expf(l1 - nm1);
      ex2 = __expf(l2 - nm2);
      ex3 = __expf(l3 - nm3);
    }
    // chunk sums
    float s0 = ex0, s1 = ex1, s2 = ex2, s3 = ex3;
#pragma unroll
    for (int off = 1; off < 64; off <<= 1) {
      s0 += __shfl_xor(s0, off);
      s1 += __shfl_xor(s1, off);
      s2 += __shfl_xor(s2, off);
      s3 += __shfl_xor(s3, off);
    }
    d0 = d0 * sc0 + s0; d1 = d1 * sc1 + s1;
    d2 = d2 * sc2 + s2; d3 = d3 * sc3 + s3;
    float msc = (head == 0) ? sc0 : (head == 1) ? sc1 : (head == 2) ? sc2 : sc3;
    accA.x *= msc; accA.y *= msc; accA.z *= msc; accA.w *= msc;
    accB.x *= msc; accB.y *= msc; accB.z *= msc; accB.w *= msc;
    m0 = nm0; m1 = nm1; m2 = nm2; m3 = nm3;
    float exh = (head == 0) ? ex0 : (head == 1) ? ex1 : (head == 2) ? ex2 : ex3;
    // gather: broadcast (src, alpha-numerator) from lane j via shuffles; 4 edges in flight
    int j = 0;
    for (; j + 4 <= m; j += 4) {
      int sj0 = __shfl(s, j), sj1 = __shfl(s, j + 1);
      int sj2 = __shfl(s, j + 2), sj3 = __shfl(s, j + 3);
      float a0 = __shfl(exh, j), a1 = __shfl(exh, j + 1);
      float a2 = __shfl(exh, j + 2), a3 = __shfl(exh, j + 3);
      const float4* p0 = reinterpret_cast<const float4*>(&h[(size_t)sj0 * OUTC + c0]);
      const float4* p1 = reinterpret_cast<const float4*>(&h[(size_t)sj1 * OUTC + c0]);
      const float4* p2 = reinterpret_cast<const float4*>(&h[(size_t)sj2 * OUTC + c0]);
      const float4* p3 = reinterpret_cast<const float4*>(&h[(size_t)sj3 * OUTC + c0]);
      float4 h0a = p0[0], h0b = p0[1];
      float4 h1a = p1[0], h1b = p1[1];
      float4 h2a = p2[0], h2b = p2[1];
      float4 h3a = p3[0], h3b = p3[1];
      accA.x += a0 * h0a.x; accA.y += a0 * h0a.y; accA.z += a0 * h0a.z; accA.w += a0 * h0a.w;
      accB.x += a0 * h0b.x; accB.y += a0 * h0b.y; accB.z += a0 * h0b.z; accB.w += a0 * h0b.w;
      accA.x += a1 * h1a.x; accA.y += a1 * h1a.y; accA.z += a1 * h1a.z; accA.w += a1 * h1a.w;
      accB.x += a1 * h1b.x; accB.y += a1 * h1b.y; accB.z += a1 * h1b.z; accB.w += a1 * h1b.w;
      accA.x += a2 * h2a.x; accA.y += a2 * h2a.y; accA.z += a2 * h2a.z; accA.w += a2 * h2a.w;
      accB.x += a2 * h2b.x; accB.y += a2 * h2b.y; accB.z += a2 * h2b.z; accB.w += a2 * h2b.w;
      accA.x += a3 * h3a.x; accA.y += a3 * h3a.y; accA.z += a3 * h3a.z; accA.w += a3 * h3a.w;
      accB.x += a3 * h3b.x; accB.y += a3 * h3b.y; accB.z += a3 * h3b.z; accB.w += a3 * h3b.w;
    }
    for (; j < m; ++j) {
      int sj = __shfl(s, j);
      float a = __shfl(exh, j);
      const float4* p = reinterpret_cast<const float4*>(&h[(size_t)sj * OUTC + c0]);
      float4 ha = p[0], hb = p[1];
      accA.x += a * ha.x; accA.y += a * ha.y; accA.z += a * ha.z; accA.w += a * ha.w;
      accB.x += a * hb.x; accB.y += a * hb.y; accB.z += a * hb.z; accB.w += a * hb.w;
    }
  }
  // normalize by denom (per-head), then sum across the 4 head-lanes (l^16, l^32)
  float dh = (head == 0) ? d0 : (head == 1) ? d1 : (head == 2) ? d2 : d3;
  float inv = 1.f / dh;
  accA.x *= inv; accA.y *= inv; accA.z *= inv; accA.w *= inv;
  accB.x *= inv; accB.y *= inv; accB.z *= inv; accB.w *= inv;
#pragma unroll
  for (int off = 16; off < 64; off <<= 1) {
    accA.x += __shfl_xor(accA.x, off); accA.y += __shfl_xor(accA.y, off);
    accA.z += __shfl_xor(accA.z, off); accA.w += __shfl_xor(accA.w, off);
    accB.x += __shfl_xor(accB.x, off); accB.y += __shfl_xor(accB.y, off);
    accB.z += __shfl_xor(accB.z, off); accB.w += __shfl_xor(accB.w, off);
  }
  if (lane < 16) {
    int cc = lane * 8;
    float4 b0 = *reinterpret_cast<const float4*>(&bias[cc]);
    float4 b1 = *reinterpret_cast<const float4*>(&bias[cc + 4]);
    float4 o0, o1;
    o0.x = fmaxf(accA.x * 0.25f + b0.x, 0.f);
    o0.y = fmaxf(accA.y * 0.25f + b0.y, 0.f);
    o0.z = fmaxf(accA.z * 0.25f + b0.z, 0.f);
    o0.w = fmaxf(accA.w * 0.25f + b0.w, 0.f);
    o1.x = fmaxf(accB.x * 0.25f + b1.x, 0.f);
    o1.y = fmaxf(accB.y * 0.25f + b1.y, 0.f);
    o1.z = fmaxf(accB.z * 0.25f + b1.z, 0.f);
    o1.w = fmaxf(accB.w * 0.25f + b1.w, 0.f);
    *reinterpret_cast<float4*>(&xout[(size_t)n * HID + cc]) = o0;
    *reinterpret_cast<float4*>(&xout[(size_t)n * HID + cc + 4]) = o1;
  }
}

// ---------------- global mean pool: partial sums + atomics ----------------
#define POOL_NB 128   // nodes per block
__global__ void k_pool(const float* __restrict__ x, const int* __restrict__ batch,
                       float* __restrict__ sums) {
  int b = blockIdx.x;
  int tid = threadIdx.x;  // 256
  int ch = tid & 127, par = tid >> 7;
  int nb = b * POOL_NB;
  int ne = min(nb + POOL_NB, NN);
  float acc = 0.f;
  int cur = -1;
  for (int node = nb + par; node < ne; node += 2) {
    int g = batch[node];
    if (g != cur) {
      if (cur >= 0) atomicAdd(&sums[cur * HID + ch], acc);
      cur = g; acc = 0.f;
    }
    acc += x[(size_t)node * HID + ch];
  }
  if (cur >= 0) atomicAdd(&sums[cur * HID + ch], acc);
}

// ---------------- MLP head (counts via binary search over sorted batch) ----------------
__global__ void k_mlp(const float* __restrict__ sums, const int* __restrict__ batch,
                      const float* __restrict__ bst, const float* __restrict__ M1,
                      const float* __restrict__ mb1, const float* __restrict__ M2,
                      const float* __restrict__ mb2, const float* __restrict__ M3,
                      const float* __restrict__ mb3, float* __restrict__ out) {
  int g = blockIdx.x, tid = threadIdx.x;  // 128 threads
  int lo = 0, hi = NN;
  while (lo < hi) { int mid = (lo + hi) >> 1; if (batch[mid] < g) lo = mid + 1; else hi = mid; }
  int s = lo;
  lo = s; hi = NN;
  while (lo < hi) { int mid = (lo + hi) >> 1; if (batch[mid] < g + 1) lo = mid + 1; else hi = mid; }
  int e = lo;
  float cnt = (float)(e - s);
  float pooled = sums[g * HID + tid] / fmaxf(cnt, 1.f);
  __shared__ float z[HID + 1];
  __shared__ float z1[HID];
  __shared__ float z2[64];
  z[tid] = pooled;
  if (tid == 0) z[HID] = log1pf(bst[g]);
  __syncthreads();
  float a1 = mb1[tid];
  for (int k = 0; k < HID + 1; ++k) a1 += z[k] * M1[k * HID + tid];
  z1[tid] = a1 > 0.f ? a1 : 0.f;
  __syncthreads();
  if (tid < 64) {
    float a2 = mb2[tid];
    for (int k = 0; k < HID; ++k) a2 += z1[k] * M2[k * 64 + tid];
    z2[tid] = a2 > 0.f ? a2 : 0.f;
  }
  __syncthreads();
  if (tid < 2) {
    float a3 = mb3[tid];
    for (int k = 0; k < 64; ++k) a3 += z2[k] * M3[k * 2 + tid];
    out[g * 2 + tid] = a3;
  }
}

extern "C" void kernel_launch(void* const* d_in, const int* in_sizes, int n_in,
                              void* d_out, int out_size, void* d_ws, size_t ws_size,
                              hipStream_t stream) {
  const float* x   = (const float*)d_in[0];
  const int*   ei  = (const int*)d_in[1];
  const int*   bat = (const int*)d_in[2];
  const float* bst = (const float*)d_in[3];
  const float* W1 = (const float*)d_in[4];
  const float* as1 = (const float*)d_in[5];
  const float* ad1 = (const float*)d_in[6];
  const float* b1 = (const float*)d_in[7];
  const float* W2 = (const float*)d_in[8];
  const float* as2 = (const float*)d_in[9];
  const float* ad2 = (const float*)d_in[10];
  const float* b2 = (const float*)d_in[11];
  const float* W3 = (const float*)d_in[12];
  const float* as3 = (const float*)d_in[13];
  const float* ad3 = (const float*)d_in[14];
  const float* b3 = (const float*)d_in[15];
  const float* M1 = (const float*)d_in[16];
  const float* mb1 = (const float*)d_in[17];
  const float* M2 = (const float*)d_in[18];
  const float* mb2 = (const float*)d_in[19];
  const float* M3 = (const float*)d_in[20];
  const float* mb3 = (const float*)d_in[21];
  float* out = (float*)d_out;

  char* ws = (char*)d_ws;
  auto alloc = [&](size_t bytes) -> void* {
    void* p = (void*)ws;
    ws += (bytes + 255) & ~(size_t)255;
    return p;
  };
  float* h_buf  = (float*)alloc((size_t)NN * OUTC * 4);
  float* x_buf  = (float*)alloc((size_t)NN * HID * 4);
  float* e_src  = (float*)alloc((size_t)NN * 4 * 4);
  float* e_dst  = (float*)alloc((size_t)NN * 4 * 4);
  int*   deg    = (int*)alloc((size_t)NN * 4);
  int*   rowst  = (int*)alloc((size_t)(NN + 1) * 4);
  int*   cursor = (int*)alloc((size_t)NN * 4);
  int*   csr    = (int*)alloc((size_t)ET * 4);
  float* gsums  = (float*)alloc((size_t)NG * HID * 4);

  // CSR by destination
  hipMemsetAsync(deg, 0, (size_t)NN * 4, stream);
  k_hist<<<(ET + 255) / 256, 256, 0, stream>>>(ei, deg);
  k_scan<<<1, 1024, 0, stream>>>(deg, rowst, cursor);
  k_scatter<<<(ET + 255) / 256, 256, 0, stream>>>(ei, cursor, csr);

  dim3 ggrid(OUTC / 64, (NN + 63) / 64);
  dim3 agrid((NN + 3) / 4);
  // layer 1
  k_gemm_t<12, 12><<<ggrid, 256, 0, stream>>>(x, W1, h_buf);
  k_esd<<<NN, 128, 0, stream>>>(h_buf, as1, ad1, e_src, e_dst);
  k_agg<<<agrid, 256, 0, stream>>>(h_buf, e_src, e_dst, rowst, csr, b1, x_buf);
  // layer 2
  k_gemm_t<128, 64><<<ggrid, 256, 0, stream>>>(x_buf, W2, h_buf);
  k_esd<<<NN, 128, 0, stream>>>(h_buf, as2, ad2, e_src, e_dst);
  k_agg<<<agrid, 256, 0, stream>>>(h_buf, e_src, e_dst, rowst, csr, b2, x_buf);
  // layer 3
  k_gemm_t<128, 64><<<ggrid, 256, 0, stream>>>(x_buf, W3, h_buf);
  k_esd<<<NN, 128, 0, stream>>>(h_buf, as3, ad3, e_src, e_dst);
  k_agg<<<agrid, 256, 0, stream>>>(h_buf, e_src, e_dst, rowst, csr, b3, x_buf);
  // pool + MLP
  hipMemsetAsync(gsums, 0, (size_t)NG * HID * 4, stream);
  k_pool<<<(NN + POOL_NB - 1) / POOL_NB, 256, 0, stream>>>(x_buf, bat, gsums);
  k_mlp<<<NG, 128, 0, stream>>>(gsums, bat, bst, M1, mb1, M2, mb2, M3, mb3, out);
}